// Round 15
// baseline (34.585 us; speedup 1.0000x reference)
//
#include <hip/hip_runtime.h>

#define NQ   10
#define NL   4
#define NCL  10
#define PI_F 3.14159265358979f

typedef float f2 __attribute__((ext_vector_type(2)));

// ---- forced VOP3P packed-f32 (validated R13: correct, perf-neutral, compact) ----
__device__ __forceinline__ f2 pk_mul2(f2 a, f2 b) {
    f2 d; asm("v_pk_mul_f32 %0, %1, %2" : "=v"(d) : "v"(a), "v"(b)); return d;
}
__device__ __forceinline__ f2 pk_fma2(f2 a, f2 b, f2 c) {   // a*b + c
    f2 d; asm("v_pk_fma_f32 %0, %1, %2, %3" : "=v"(d) : "v"(a), "v"(b), "v"(c)); return d;
}
__device__ __forceinline__ f2 pk_add2(f2 a, f2 b) {
    f2 d; asm("v_pk_add_f32 %0, %1, %2" : "=v"(d) : "v"(a), "v"(b)); return d;
}

__device__ __forceinline__ float bcastf(float v, int l) {
    return __int_as_float(__builtin_amdgcn_readlane(__float_as_int(v), l));
}
__device__ __forceinline__ float bperm(int byteaddr, float v) {
    return __int_as_float(__builtin_amdgcn_ds_bpermute(byteaddr, __float_as_int(v)));
}

// Cross-lane xor-butterfly fetch (validated R5-R14).
template<int M>
__device__ __forceinline__ float xlane(float v) {
    if constexpr (M == 1) {
        return __int_as_float(__builtin_amdgcn_update_dpp(
            __float_as_int(v), __float_as_int(v), 0xB1, 0xF, 0xF, false));
    } else if constexpr (M == 2) {
        return __int_as_float(__builtin_amdgcn_update_dpp(
            __float_as_int(v), __float_as_int(v), 0x4E, 0xF, 0xF, false));
    } else if constexpr (M == 4) {
        return __int_as_float(__builtin_amdgcn_ds_swizzle(
            __float_as_int(v), 0x101F));
    } else if constexpr (M == 8) {
        return __int_as_float(__builtin_amdgcn_update_dpp(
            __float_as_int(v), __float_as_int(v), 0x128, 0xF, 0xF, false));
    } else if constexpr (M == 16) {
        auto r = __builtin_amdgcn_permlane16_swap(
            (unsigned)__float_as_int(v), (unsigned)__float_as_int(v), false, false);
        return __int_as_float((int)(r[0] ^ r[1] ^ (unsigned)__float_as_int(v)));
    } else {
        auto r = __builtin_amdgcn_permlane32_swap(
            (unsigned)__float_as_int(v), (unsigned)__float_as_int(v), false, false);
        return __int_as_float((int)(r[0] ^ r[1] ^ (unsigned)__float_as_int(v)));
    }
}
template<int M>
__device__ __forceinline__ f2 xlane2(f2 v) {
    f2 r; r.x = xlane<M>(v.x); r.y = xlane<M>(v.y); return r;
}

// RY on a lane-bit wire, DUAL element: A/B chains interleaved per register.
template<int M>
__device__ __forceinline__ void xwireD(float c, float s, int lane,
                                       f2 (&sa)[16], f2 (&sb)[16]) {
    const float se = (lane & M) ? s : -s;
    const f2 c2 = {c, c}, se2 = {se, se};
    #pragma unroll
    for (int r = 0; r < 16; ++r) {
        f2 ta = xlane2<M>(sa[r]);
        f2 tb = xlane2<M>(sb[r]);
        sa[r] = pk_fma2(se2, ta, pk_mul2(c2, sa[r]));
        sb[r] = pk_fma2(se2, tb, pk_mul2(c2, sb[r]));
    }
}

__device__ __forceinline__ f2 bsum2(f2 v) {
    v = pk_add2(v, xlane2<1 >(v));
    v = pk_add2(v, xlane2<2 >(v));
    v = pk_add2(v, xlane2<4 >(v));
    v = pk_add2(v, xlane2<8 >(v));
    v = pk_add2(v, xlane2<16>(v));
    v = pk_add2(v, xlane2<32>(v));
    return v;
}

// Walsh transform over lanes (in place).
__device__ __forceinline__ float walsh(float P, int lane) {
    float t;
    t = xlane<1 >(P); P = t + ((lane & 1 ) ? -P : P);
    t = xlane<2 >(P); P = t + ((lane & 2 ) ? -P : P);
    t = xlane<4 >(P); P = t + ((lane & 4 ) ? -P : P);
    t = xlane<8 >(P); P = t + ((lane & 8 ) ? -P : P);
    t = xlane<16>(P); P = t + ((lane & 16) ? -P : P);
    t = xlane<32>(P); P = t + ((lane & 32) ? -P : P);
    return P;
}

// Layout: ONE wave carries TWO batch elements (A = 2*gw, B = 2*gw+1).
// Per element: lane l holds amplitudes d=(l<<4)|r as f2{re,im};
// register bits = qubits 0..3, lane bits = qubits 4..9.
// The A and B dependency chains are independent -> in-wave ILP fills stalls
// (co-resident identical waves convoy on the same DS/DPP ops; a second
// in-wave chain cannot).
__global__ __launch_bounds__(256)
void qnn_kernel(const float* __restrict__ x,
                const float* __restrict__ W_pre,
                const float* __restrict__ b_pre,
                const float* __restrict__ weights,
                const float* __restrict__ W_post,
                const float* __restrict__ b_post,
                float* __restrict__ out, int batch)
{
    const int lane = threadIdx.x & 63;
    const int gw = blockIdx.x * 4 + (threadIdx.x >> 6);
    const int b0 = gw * 2;
    if (b0 >= batch) return;
    const int b1 = b0 + 1;          // batch is even (2048); b1 < batch
    const int bu0 = __builtin_amdgcn_readfirstlane(b0);
    const int bu1 = __builtin_amdgcn_readfirstlane(b1);

    // 50 half-angle cos/sin pairs: lane j<50 owns weight j (shared by A and B).
    float cw = 0.0f, sw = 0.0f;
    if (lane < (NL + 1) * NQ) {
        float th = 0.5f * weights[lane];
        __sincosf(th, &sw, &cw);
    }

    // h = x @ W_pre.T + b_pre for BOTH elements (uniform addresses).
    float hA[NQ], hB[NQ];
    {
        float xvA[NQ], xvB[NQ];
        #pragma unroll
        for (int k = 0; k < NQ; ++k) { xvA[k] = x[bu0 * NQ + k]; xvB[k] = x[bu1 * NQ + k]; }
        #pragma unroll
        for (int j = 0; j < NQ; ++j) {
            float aA = b_pre[j], aB = aA;
            #pragma unroll
            for (int k = 0; k < NQ; ++k) {
                const float wjk = W_pre[j * NQ + k];
                aA = fmaf(xvA[k], wjk, aA);
                aB = fmaf(xvB[k], wjk, aB);
            }
            hA[j] = aA; hB[j] = aB;
        }
    }
    float zA[NQ - 1], zB[NQ - 1];
    #pragma unroll
    for (int i = 0; i < NQ - 1; ++i) {
        zA[i] = (PI_F - hA[i]) * (PI_F - hA[i + 1]);
        zB[i] = (PI_F - hB[i]) * (PI_F - hB[i + 1]);
    }

    // Lane-constant angle parts.
    float AA = 0.0f, AB = 0.0f;
    #pragma unroll
    for (int i = 4; i < NQ; ++i) {
        const bool n = (lane >> (i - 4)) & 1;
        AA += n ? -hA[i] : hA[i];
        AB += n ? -hB[i] : hB[i];
    }
    #pragma unroll
    for (int i = 4; i < NQ - 1; ++i) {
        const bool n = ((lane >> (i - 4)) ^ (lane >> (i - 3))) & 1;
        AA += n ? -zA[i] : zA[i];
        AB += n ? -zB[i] : zB[i];
    }

    // State init: (1/32) e^{-i ang}, both elements.
    f2 sa[16], sb[16];
    #pragma unroll
    for (int r = 0; r < 16; ++r) {
        float angA = AA, angB = AB;
        #pragma unroll
        for (int i = 0; i < 4; ++i) {
            if ((r >> i) & 1) { angA -= hA[i]; angB -= hB[i]; }
            else              { angA += hA[i]; angB += hB[i]; }
        }
        #pragma unroll
        for (int i = 0; i < 3; ++i) {
            if (((r >> i) ^ (r >> (i + 1))) & 1) { angA -= zA[i]; angB -= zB[i]; }
            else                                 { angA += zA[i]; angB += zB[i]; }
        }
        if (((r >> 3) ^ lane) & 1) { angA -= zA[3]; angB -= zB[3]; }
        else                       { angA += zA[3]; angB += zB[3]; }
        float snA, cnA, snB, cnB;
        __sincosf(angA, &snA, &cnA);
        __sincosf(angB, &snB, &cnB);
        sa[r].x = 0.03125f * cnA; sa[r].y = -0.03125f * snA;
        sb[r].x = 0.03125f * cnB; sb[r].y = -0.03125f * snB;
    }

    // CNOT-chain perm lane part: l' = ((l ^ (l<<1)) & 0x3F) ^ r3.
    const int plbase = (lane ^ (lane << 1)) & 0x3F;
    const int paddr0 = plbase << 2;
    const int paddr1 = (plbase ^ 1) << 2;

    #pragma clang loop unroll(disable)
    for (int l = 0; l <= NL; ++l) {
        if (l > 0) {
            // Perm element A then B (32 independent bperms each pipeline fine;
            // sequencing halves the np[] register spike).
            f2 np[16];
            #pragma unroll
            for (int r = 0; r < 16; ++r) {
                const int rp = (r ^ (r << 1)) & 0xF;
                const int pa = (r < 8) ? paddr0 : paddr1;
                np[r].x = bperm(pa, sa[rp].x);
                np[r].y = bperm(pa, sa[rp].y);
            }
            #pragma unroll
            for (int r = 0; r < 16; ++r) sa[r] = np[r];
            #pragma unroll
            for (int r = 0; r < 16; ++r) {
                const int rp = (r ^ (r << 1)) & 0xF;
                const int pa = (r < 8) ? paddr0 : paddr1;
                np[r].x = bperm(pa, sb[rp].x);
                np[r].y = bperm(pa, sb[rp].y);
            }
            #pragma unroll
            for (int r = 0; r < 16; ++r) sb[r] = np[r];
        }

        const int base = l * NQ;

        // Wires 0..3: in-register butterflies, dual interleaved.
        #pragma unroll
        for (int w = 0; w < 4; ++w) {
            const float c = bcastf(cw, base + w);
            const float s = bcastf(sw, base + w);
            const f2 c2 = {c, c}, s2 = {s, s}, ns2 = {-s, -s};
            #pragma unroll
            for (int r = 0; r < 16; ++r) {
                if (r & (1 << w)) continue;
                const int q = r | (1 << w);
                f2 a0 = sa[r], a1 = sa[q];
                f2 b0_ = sb[r], b1_ = sb[q];
                sa[r] = pk_fma2(ns2, a1, pk_mul2(c2, a0));
                sb[r] = pk_fma2(ns2, b1_, pk_mul2(c2, b0_));
                sa[q] = pk_fma2(s2,  a0, pk_mul2(c2, a1));
                sb[q] = pk_fma2(s2,  b0_, pk_mul2(c2, b1_));
            }
        }

        // Wires 4..9: lane-bit butterflies, dual interleaved.
        xwireD<1 >(bcastf(cw, base + 4), bcastf(sw, base + 4), lane, sa, sb);
        xwireD<2 >(bcastf(cw, base + 5), bcastf(sw, base + 5), lane, sa, sb);
        xwireD<4 >(bcastf(cw, base + 6), bcastf(sw, base + 6), lane, sa, sb);
        xwireD<8 >(bcastf(cw, base + 7), bcastf(sw, base + 7), lane, sa, sb);
        xwireD<16>(bcastf(cw, base + 8), bcastf(sw, base + 8), lane, sa, sb);
        xwireD<32>(bcastf(cw, base + 9), bcastf(sw, base + 9), lane, sa, sb);
    }

    // Probabilities and q_k, both elements.
    float PA = 0.0f, a0s = 0.0f, a1s = 0.0f, a2s = 0.0f, a3s = 0.0f;
    float PB = 0.0f, b0s = 0.0f, b1s = 0.0f, b2s = 0.0f, b3s = 0.0f;
    #pragma unroll
    for (int r = 0; r < 16; ++r) {
        f2 qa = pk_mul2(sa[r], sa[r]);
        f2 qb = pk_mul2(sb[r], sb[r]);
        float pA = qa.x + qa.y, pB = qb.x + qb.y;
        PA += pA; PB += pB;
        a0s += (r & 1) ? -pA : pA;  b0s += (r & 1) ? -pB : pB;
        a1s += (r & 2) ? -pA : pA;  b1s += (r & 2) ? -pB : pB;
        a2s += (r & 4) ? -pA : pA;  b2s += (r & 4) ? -pB : pB;
        a3s += (r & 8) ? -pA : pA;  b3s += (r & 8) ? -pB : pB;
    }
    f2 qa01 = bsum2((f2){a0s, a1s});
    f2 qb01 = bsum2((f2){b0s, b1s});
    f2 qa23 = bsum2((f2){a2s, a3s});
    f2 qb23 = bsum2((f2){b2s, b3s});
    PA = walsh(PA, lane);
    PB = walsh(PB, lane);

    float qA[NCL], qB[NCL];
    qA[0] = qa01.x; qA[1] = qa01.y; qA[2] = qa23.x; qA[3] = qa23.y;
    qB[0] = qb01.x; qB[1] = qb01.y; qB[2] = qb23.x; qB[3] = qb23.y;
    qA[4] = bcastf(PA, 1);  qB[4] = bcastf(PB, 1);
    qA[5] = bcastf(PA, 2);  qB[5] = bcastf(PB, 2);
    qA[6] = bcastf(PA, 4);  qB[6] = bcastf(PB, 4);
    qA[7] = bcastf(PA, 8);  qB[7] = bcastf(PB, 8);
    qA[8] = bcastf(PA, 16); qB[8] = bcastf(PB, 16);
    qA[9] = bcastf(PA, 32); qB[9] = bcastf(PB, 32);

    if (lane < NCL) {
        float oA = b_post[lane], oB = oA;
        #pragma unroll
        for (int k = 0; k < NCL; ++k) {
            const float wpk = W_post[lane * NQ + k];
            oA = fmaf(qA[k], wpk, oA);
            oB = fmaf(qB[k], wpk, oB);
        }
        out[b0 * NCL + lane] = oA;
        out[b1 * NCL + lane] = oB;
    }
}

extern "C" void kernel_launch(void* const* d_in, const int* in_sizes, int n_in,
                              void* d_out, int out_size, void* d_ws, size_t ws_size,
                              hipStream_t stream) {
    const float* x       = (const float*)d_in[0];
    const float* W_pre   = (const float*)d_in[1];
    const float* b_pre   = (const float*)d_in[2];
    const float* weights = (const float*)d_in[3];
    const float* W_post  = (const float*)d_in[4];
    const float* b_post  = (const float*)d_in[5];
    float* outp = (float*)d_out;
    int batch = in_sizes[0] / NQ;
    int waves = (batch + 1) / 2;
    int grid  = (waves + 3) / 4;
    qnn_kernel<<<grid, 256, 0, stream>>>(x, W_pre, b_pre, weights, W_post, b_post, outp, batch);
}

// Round 18
// 28.088 us; speedup vs baseline: 1.2313x; 1.2313x over previous
//
#include <hip/hip_runtime.h>

#define NQ   10
#define NL   4
#define NCL  10
#define PI_F 3.14159265358979f

typedef float f2 __attribute__((ext_vector_type(2)));

// ---- forced VOP3P packed-f32 (validated R13) ----
__device__ __forceinline__ f2 pk_mul2(f2 a, f2 b) {
    f2 d; asm("v_pk_mul_f32 %0, %1, %2" : "=v"(d) : "v"(a), "v"(b)); return d;
}
__device__ __forceinline__ f2 pk_fma2(f2 a, f2 b, f2 c) {   // a*b + c
    f2 d; asm("v_pk_fma_f32 %0, %1, %2, %3" : "=v"(d) : "v"(a), "v"(b), "v"(c)); return d;
}
__device__ __forceinline__ f2 pk_add2(f2 a, f2 b) {
    f2 d; asm("v_pk_add_f32 %0, %1, %2" : "=v"(d) : "v"(a), "v"(b)); return d;
}

__device__ __forceinline__ float bcastf(float v, int l) {
    return __int_as_float(__builtin_amdgcn_readlane(__float_as_int(v), l));
}
__device__ __forceinline__ float bperm(int byteaddr, float v) {
    return __int_as_float(__builtin_amdgcn_ds_bpermute(byteaddr, __float_as_int(v)));
}

// Cross-lane xor-butterfly fetch (validated R5-R15).
// m16/m32: partner = (r0==own) ? r1 : r0  — direction-proof, 2 VALU.
template<int M>
__device__ __forceinline__ float xlane(float v) {
    if constexpr (M == 1) {
        return __int_as_float(__builtin_amdgcn_update_dpp(
            __float_as_int(v), __float_as_int(v), 0xB1, 0xF, 0xF, false));
    } else if constexpr (M == 2) {
        return __int_as_float(__builtin_amdgcn_update_dpp(
            __float_as_int(v), __float_as_int(v), 0x4E, 0xF, 0xF, false));
    } else if constexpr (M == 4) {
        return __int_as_float(__builtin_amdgcn_ds_swizzle(
            __float_as_int(v), 0x101F));
    } else if constexpr (M == 8) {
        return __int_as_float(__builtin_amdgcn_update_dpp(
            __float_as_int(v), __float_as_int(v), 0x128, 0xF, 0xF, false));
    } else if constexpr (M == 16) {
        unsigned own = (unsigned)__float_as_int(v);
        auto r = __builtin_amdgcn_permlane16_swap(own, own, false, false);
        unsigned p = (r[0] == own) ? (unsigned)r[1] : (unsigned)r[0];
        return __int_as_float((int)p);
    } else {
        unsigned own = (unsigned)__float_as_int(v);
        auto r = __builtin_amdgcn_permlane32_swap(own, own, false, false);
        unsigned p = (r[0] == own) ? (unsigned)r[1] : (unsigned)r[0];
        return __int_as_float((int)p);
    }
}
template<int M>
__device__ __forceinline__ f2 xlane2(f2 v) {
    f2 r; r.x = xlane<M>(v.x); r.y = xlane<M>(v.y); return r;
}

// RY on a lane-bit wire (packed): sc' = se*partner + c*sc.
template<int M>
__device__ __forceinline__ void xwire2(float c, float s, int lane, f2 (&sc)[16]) {
    const float se = (lane & M) ? s : -s;
    const f2 c2 = {c, c}, se2 = {se, se};
    f2 t[16];
    #pragma unroll
    for (int r = 0; r < 16; ++r) t[r] = xlane2<M>(sc[r]);
    #pragma unroll
    for (int r = 0; r < 16; ++r) sc[r] = pk_fma2(se2, t[r], pk_mul2(c2, sc[r]));
}

__device__ __forceinline__ f2 bsum2(f2 v) {
    v = pk_add2(v, xlane2<1 >(v));
    v = pk_add2(v, xlane2<2 >(v));
    v = pk_add2(v, xlane2<4 >(v));
    v = pk_add2(v, xlane2<8 >(v));
    v = pk_add2(v, xlane2<16>(v));
    v = pk_add2(v, xlane2<32>(v));
    return v;
}

// Layout: ONE wave per batch element, ONE element per 64-thread block.
// Small blocks -> 8 independent blocks/CU, fine-grained drain (fixes the
// measured 5/8 average occupancy from 4-wave blocks).
// Lane l holds amplitudes d = (l<<4)|r as f2{re,im}:
// register bits = qubits 0..3, lane bits = qubits 4..9.
__global__ __launch_bounds__(64)
void qnn_kernel(const float* __restrict__ x,
                const float* __restrict__ W_pre,
                const float* __restrict__ b_pre,
                const float* __restrict__ weights,
                const float* __restrict__ W_post,
                const float* __restrict__ b_post,
                float* __restrict__ out, int batch)
{
    const int lane = threadIdx.x;
    const int b = blockIdx.x;          // uniform (scalar) element index

    // 50 half-angle cos/sin pairs: lane j<50 owns weight j.
    float cw = 0.0f, sw = 0.0f;
    if (lane < (NL + 1) * NQ) {
        float th = 0.5f * weights[lane];
        __sincosf(th, &sw, &cw);
    }

    // h = x @ W_pre.T + b_pre : all lanes, uniform (scalarizable) addresses.
    float xv[NQ];
    #pragma unroll
    for (int k = 0; k < NQ; ++k) xv[k] = x[b * NQ + k];
    float h[NQ];
    #pragma unroll
    for (int j = 0; j < NQ; ++j) {
        float acc = b_pre[j];
        #pragma unroll
        for (int k = 0; k < NQ; ++k)
            acc = fmaf(xv[k], W_pre[j * NQ + k], acc);
        h[j] = acc;
    }
    float z[NQ - 1];
    #pragma unroll
    for (int i = 0; i < NQ - 1; ++i) z[i] = (PI_F - h[i]) * (PI_F - h[i + 1]);

    // Lane-constant angle part (qubits 4..9, zz pairs (4,5)..(8,9)).
    float A = 0.0f;
    #pragma unroll
    for (int i = 4; i < NQ; ++i)
        A += ((lane >> (i - 4)) & 1) ? -h[i] : h[i];
    #pragma unroll
    for (int i = 4; i < NQ - 1; ++i)
        A += (((lane >> (i - 4)) ^ (lane >> (i - 3))) & 1) ? -z[i] : z[i];

    // State init: (1/32) e^{-i ang}.
    f2 sc[16];
    #pragma unroll
    for (int r = 0; r < 16; ++r) {
        float ang = A;
        #pragma unroll
        for (int i = 0; i < 4; ++i)
            ang += ((r >> i) & 1) ? -h[i] : h[i];
        #pragma unroll
        for (int i = 0; i < 3; ++i)
            ang += (((r >> i) ^ (r >> (i + 1))) & 1) ? -z[i] : z[i];
        ang += (((r >> 3) ^ lane) & 1) ? -z[3] : z[3];
        float sn, cn;
        __sincosf(ang, &sn, &cn);
        sc[r].x = 0.03125f * cn;
        sc[r].y = -0.03125f * sn;
    }

    // CNOT-chain perm lane part: l' = ((l ^ (l<<1)) & 0x3F) ^ r3.
    const int plbase = (lane ^ (lane << 1)) & 0x3F;
    const int paddr0 = plbase << 2;
    const int paddr1 = (plbase ^ 1) << 2;

    #pragma clang loop unroll(disable)
    for (int l = 0; l <= NL; ++l) {
        if (l > 0) {
            // new[(l,r)] = old[(l', r')], r' = (r ^ (r<<1)) & 0xF
            f2 np[16];
            #pragma unroll
            for (int r = 0; r < 16; ++r) {
                const int rp = (r ^ (r << 1)) & 0xF;
                const int pa = (r < 8) ? paddr0 : paddr1;
                np[r].x = bperm(pa, sc[rp].x);
                np[r].y = bperm(pa, sc[rp].y);
            }
            #pragma unroll
            for (int r = 0; r < 16; ++r) sc[r] = np[r];
        }

        const int base = l * NQ;

        // Wires 0..3: in-register butterflies, forced-packed.
        #pragma unroll
        for (int w = 0; w < 4; ++w) {
            const float c = bcastf(cw, base + w);
            const float s = bcastf(sw, base + w);
            const f2 c2 = {c, c}, s2 = {s, s}, ns2 = {-s, -s};
            #pragma unroll
            for (int r = 0; r < 16; ++r) {
                if (r & (1 << w)) continue;
                const int q = r | (1 << w);
                f2 a0 = sc[r], a1 = sc[q];
                sc[r] = pk_fma2(ns2, a1, pk_mul2(c2, a0));   // c*a0 - s*a1
                sc[q] = pk_fma2(s2,  a0, pk_mul2(c2, a1));   // s*a0 + c*a1
            }
        }

        // Wires 4..9: lane-bit butterflies.
        xwire2<1 >(bcastf(cw, base + 4), bcastf(sw, base + 4), lane, sc);
        xwire2<2 >(bcastf(cw, base + 5), bcastf(sw, base + 5), lane, sc);
        xwire2<4 >(bcastf(cw, base + 6), bcastf(sw, base + 6), lane, sc);
        xwire2<8 >(bcastf(cw, base + 7), bcastf(sw, base + 7), lane, sc);
        xwire2<16>(bcastf(cw, base + 8), bcastf(sw, base + 8), lane, sc);
        xwire2<32>(bcastf(cw, base + 9), bcastf(sw, base + 9), lane, sc);
    }

    // Probabilities and q_k.
    float P = 0.0f, p0 = 0.0f, p1 = 0.0f, p2 = 0.0f, p3 = 0.0f;
    #pragma unroll
    for (int r = 0; r < 16; ++r) {
        f2 qq = pk_mul2(sc[r], sc[r]);
        float pr = qq.x + qq.y;
        P  += pr;
        p0 += (r & 1) ? -pr : pr;
        p1 += (r & 2) ? -pr : pr;
        p2 += (r & 4) ? -pr : pr;
        p3 += (r & 8) ? -pr : pr;
    }
    // q_0..3: packed butterfly sums (all lanes get totals).
    f2 qa = bsum2((f2){p0, p1});
    f2 qb = bsum2((f2){p2, p3});
    // q_4..9: Walsh transform of P over lanes; value at lane 2^j.
    {
        float t;
        t = xlane<1 >(P); P = t + ((lane & 1 ) ? -P : P);
        t = xlane<2 >(P); P = t + ((lane & 2 ) ? -P : P);
        t = xlane<4 >(P); P = t + ((lane & 4 ) ? -P : P);
        t = xlane<8 >(P); P = t + ((lane & 8 ) ? -P : P);
        t = xlane<16>(P); P = t + ((lane & 16) ? -P : P);
        t = xlane<32>(P); P = t + ((lane & 32) ? -P : P);
    }
    float q[NCL];
    q[0] = qa.x; q[1] = qa.y; q[2] = qb.x; q[3] = qb.y;
    q[4] = bcastf(P, 1);
    q[5] = bcastf(P, 2);
    q[6] = bcastf(P, 4);
    q[7] = bcastf(P, 8);
    q[8] = bcastf(P, 16);
    q[9] = bcastf(P, 32);

    if (lane < NCL) {
        float o = b_post[lane];
        #pragma unroll
        for (int k = 0; k < NCL; ++k)
            o = fmaf(q[k], W_post[lane * NQ + k], o);
        out[b * NCL + lane] = o;
    }
}

extern "C" void kernel_launch(void* const* d_in, const int* in_sizes, int n_in,
                              void* d_out, int out_size, void* d_ws, size_t ws_size,
                              hipStream_t stream) {
    const float* x       = (const float*)d_in[0];
    const float* W_pre   = (const float*)d_in[1];
    const float* b_pre   = (const float*)d_in[2];
    const float* weights = (const float*)d_in[3];
    const float* W_post  = (const float*)d_in[4];
    const float* b_post  = (const float*)d_in[5];
    float* outp = (float*)d_out;
    int batch = in_sizes[0] / NQ;
    qnn_kernel<<<batch, 64, 0, stream>>>(x, W_pre, b_pre, weights, W_post, b_post, outp, batch);
}

// Round 19
// 28.051 us; speedup vs baseline: 1.2329x; 1.0013x over previous
//
#include <hip/hip_runtime.h>

#define NQ   10
#define NL   4
#define NCL  10
#define PI_F 3.14159265358979f

typedef float f2 __attribute__((ext_vector_type(2)));

__device__ __forceinline__ float bcastf(float v, int l) {
    return __int_as_float(__builtin_amdgcn_readlane(__float_as_int(v), l));
}
__device__ __forceinline__ float bperm(int byteaddr, float v) {
    return __int_as_float(__builtin_amdgcn_ds_bpermute(byteaddr, __float_as_int(v)));
}

// Cross-lane xor-butterfly fetch (validated R5-R18).
// m16/m32: partner = (r0==own) ? r1 : r0  — direction-proof, 2 VALU.
template<int M>
__device__ __forceinline__ float xlane(float v) {
    if constexpr (M == 1) {
        return __int_as_float(__builtin_amdgcn_update_dpp(
            __float_as_int(v), __float_as_int(v), 0xB1, 0xF, 0xF, false));
    } else if constexpr (M == 2) {
        return __int_as_float(__builtin_amdgcn_update_dpp(
            __float_as_int(v), __float_as_int(v), 0x4E, 0xF, 0xF, false));
    } else if constexpr (M == 4) {
        return __int_as_float(__builtin_amdgcn_ds_swizzle(
            __float_as_int(v), 0x101F));
    } else if constexpr (M == 8) {
        return __int_as_float(__builtin_amdgcn_update_dpp(
            __float_as_int(v), __float_as_int(v), 0x128, 0xF, 0xF, false));
    } else if constexpr (M == 16) {
        unsigned own = (unsigned)__float_as_int(v);
        auto r = __builtin_amdgcn_permlane16_swap(own, own, false, false);
        unsigned p = (r[0] == own) ? (unsigned)r[1] : (unsigned)r[0];
        return __int_as_float((int)p);
    } else {
        unsigned own = (unsigned)__float_as_int(v);
        auto r = __builtin_amdgcn_permlane32_swap(own, own, false, false);
        unsigned p = (r[0] == own) ? (unsigned)r[1] : (unsigned)r[0];
        return __int_as_float((int)p);
    }
}
template<int M>
__device__ __forceinline__ f2 xlane2(f2 v) {
    f2 r; r.x = xlane<M>(v.x); r.y = xlane<M>(v.y); return r;
}

// RY on a lane-bit wire: plain scalar math (compiler folds DPP into v_fmac).
template<int M>
__device__ __forceinline__ void xwire2(float c, float s, int lane, f2 (&sc)[16]) {
    const float se = (lane & M) ? s : -s;
    #pragma unroll
    for (int r = 0; r < 16; ++r) {
        f2 t = xlane2<M>(sc[r]);
        sc[r].x = fmaf(c, sc[r].x, se * t.x);
        sc[r].y = fmaf(c, sc[r].y, se * t.y);
    }
}

__device__ __forceinline__ f2 bsum2(f2 v) {
    v += xlane2<1 >(v); v += xlane2<2 >(v); v += xlane2<4 >(v);
    v += xlane2<8 >(v); v += xlane2<16>(v); v += xlane2<32>(v);
    return v;
}

// Layout: ONE wave per element, ONE element per 64-thread block.
// Lane l holds amplitudes d = (l<<4)|r as f2{re,im}:
// register bits = qubits 0..3, lane bits = qubits 4..9.
// Layer loop FULLY UNROLLED: lets the scheduler software-pipeline across
// wire passes and the perm; coefficient readlanes become immediate-lane.
__global__ __launch_bounds__(64)
void qnn_kernel(const float* __restrict__ x,
                const float* __restrict__ W_pre,
                const float* __restrict__ b_pre,
                const float* __restrict__ weights,
                const float* __restrict__ W_post,
                const float* __restrict__ b_post,
                float* __restrict__ out, int batch)
{
    const int lane = threadIdx.x;
    const int b = blockIdx.x;          // uniform (scalar) element index

    // 50 half-angle cos/sin pairs: lane j<50 owns weight j.
    float cw = 0.0f, sw = 0.0f;
    if (lane < (NL + 1) * NQ) {
        float th = 0.5f * weights[lane];
        __sincosf(th, &sw, &cw);
    }

    // h = x @ W_pre.T + b_pre : all lanes, uniform (scalarizable) addresses.
    float xv[NQ];
    #pragma unroll
    for (int k = 0; k < NQ; ++k) xv[k] = x[b * NQ + k];
    float h[NQ];
    #pragma unroll
    for (int j = 0; j < NQ; ++j) {
        float acc = b_pre[j];
        #pragma unroll
        for (int k = 0; k < NQ; ++k)
            acc = fmaf(xv[k], W_pre[j * NQ + k], acc);
        h[j] = acc;
    }
    float z[NQ - 1];
    #pragma unroll
    for (int i = 0; i < NQ - 1; ++i) z[i] = (PI_F - h[i]) * (PI_F - h[i + 1]);

    // Lane-constant angle part (qubits 4..9, zz pairs (4,5)..(8,9)).
    float A = 0.0f;
    #pragma unroll
    for (int i = 4; i < NQ; ++i)
        A += ((lane >> (i - 4)) & 1) ? -h[i] : h[i];
    #pragma unroll
    for (int i = 4; i < NQ - 1; ++i)
        A += (((lane >> (i - 4)) ^ (lane >> (i - 3))) & 1) ? -z[i] : z[i];

    // State init: (1/32) e^{-i ang}.
    f2 sc[16];
    #pragma unroll
    for (int r = 0; r < 16; ++r) {
        float ang = A;
        #pragma unroll
        for (int i = 0; i < 4; ++i)
            ang += ((r >> i) & 1) ? -h[i] : h[i];
        #pragma unroll
        for (int i = 0; i < 3; ++i)
            ang += (((r >> i) ^ (r >> (i + 1))) & 1) ? -z[i] : z[i];
        ang += (((r >> 3) ^ lane) & 1) ? -z[3] : z[3];
        float sn, cn;
        __sincosf(ang, &sn, &cn);
        sc[r].x = 0.03125f * cn;
        sc[r].y = -0.03125f * sn;
    }

    // CNOT-chain perm lane part: l' = ((l ^ (l<<1)) & 0x3F) ^ r3.
    const int plbase = (lane ^ (lane << 1)) & 0x3F;
    const int paddr0 = plbase << 2;
    const int paddr1 = (plbase ^ 1) << 2;

    #pragma unroll
    for (int l = 0; l <= NL; ++l) {
        if (l > 0) {
            // new[(l,r)] = old[(l', r')], r' = (r ^ (r<<1)) & 0xF
            f2 np[16];
            #pragma unroll
            for (int r = 0; r < 16; ++r) {
                const int rp = (r ^ (r << 1)) & 0xF;
                const int pa = (r < 8) ? paddr0 : paddr1;
                np[r].x = bperm(pa, sc[rp].x);
                np[r].y = bperm(pa, sc[rp].y);
            }
            #pragma unroll
            for (int r = 0; r < 16; ++r) sc[r] = np[r];
        }

        const int base = l * NQ;   // compile-time after unroll

        // Wires 0..3: in-register butterflies (scalar math, compiler schedules).
        #pragma unroll
        for (int w = 0; w < 4; ++w) {
            const float c = bcastf(cw, base + w);
            const float s = bcastf(sw, base + w);
            #pragma unroll
            for (int r = 0; r < 16; ++r) {
                if (r & (1 << w)) continue;
                const int q = r | (1 << w);
                f2 a0 = sc[r], a1 = sc[q];
                sc[r].x = fmaf(c, a0.x, -(s * a1.x));
                sc[r].y = fmaf(c, a0.y, -(s * a1.y));
                sc[q].x = fmaf(s, a0.x, c * a1.x);
                sc[q].y = fmaf(s, a0.y, c * a1.y);
            }
        }

        // Wires 4..9: lane-bit butterflies.
        xwire2<1 >(bcastf(cw, base + 4), bcastf(sw, base + 4), lane, sc);
        xwire2<2 >(bcastf(cw, base + 5), bcastf(sw, base + 5), lane, sc);
        xwire2<4 >(bcastf(cw, base + 6), bcastf(sw, base + 6), lane, sc);
        xwire2<8 >(bcastf(cw, base + 7), bcastf(sw, base + 7), lane, sc);
        xwire2<16>(bcastf(cw, base + 8), bcastf(sw, base + 8), lane, sc);
        xwire2<32>(bcastf(cw, base + 9), bcastf(sw, base + 9), lane, sc);
    }

    // Probabilities and q_k.
    float P = 0.0f, p0 = 0.0f, p1 = 0.0f, p2 = 0.0f, p3 = 0.0f;
    #pragma unroll
    for (int r = 0; r < 16; ++r) {
        float pr = fmaf(sc[r].x, sc[r].x, sc[r].y * sc[r].y);
        P  += pr;
        p0 += (r & 1) ? -pr : pr;
        p1 += (r & 2) ? -pr : pr;
        p2 += (r & 4) ? -pr : pr;
        p3 += (r & 8) ? -pr : pr;
    }
    // q_0..3: butterfly sums (all lanes get totals).
    f2 qa = bsum2((f2){p0, p1});
    f2 qb = bsum2((f2){p2, p3});
    // q_4..9: Walsh transform of P over lanes; value at lane 2^j.
    {
        float t;
        t = xlane<1 >(P); P = t + ((lane & 1 ) ? -P : P);
        t = xlane<2 >(P); P = t + ((lane & 2 ) ? -P : P);
        t = xlane<4 >(P); P = t + ((lane & 4 ) ? -P : P);
        t = xlane<8 >(P); P = t + ((lane & 8 ) ? -P : P);
        t = xlane<16>(P); P = t + ((lane & 16) ? -P : P);
        t = xlane<32>(P); P = t + ((lane & 32) ? -P : P);
    }
    float q[NCL];
    q[0] = qa.x; q[1] = qa.y; q[2] = qb.x; q[3] = qb.y;
    q[4] = bcastf(P, 1);
    q[5] = bcastf(P, 2);
    q[6] = bcastf(P, 4);
    q[7] = bcastf(P, 8);
    q[8] = bcastf(P, 16);
    q[9] = bcastf(P, 32);

    if (lane < NCL) {
        float o = b_post[lane];
        #pragma unroll
        for (int k = 0; k < NCL; ++k)
            o = fmaf(q[k], W_post[lane * NQ + k], o);
        out[b * NCL + lane] = o;
    }
}

extern "C" void kernel_launch(void* const* d_in, const int* in_sizes, int n_in,
                              void* d_out, int out_size, void* d_ws, size_t ws_size,
                              hipStream_t stream) {
    const float* x       = (const float*)d_in[0];
    const float* W_pre   = (const float*)d_in[1];
    const float* b_pre   = (const float*)d_in[2];
    const float* weights = (const float*)d_in[3];
    const float* W_post  = (const float*)d_in[4];
    const float* b_post  = (const float*)d_in[5];
    float* outp = (float*)d_out;
    int batch = in_sizes[0] / NQ;
    qnn_kernel<<<batch, 64, 0, stream>>>(x, W_pre, b_pre, weights, W_post, b_post, outp, batch);
}